// Round 1
// baseline (1000.636 us; speedup 1.0000x reference)
//
#include <hip/hip_runtime.h>

// Segmented max pooling:
//   out[seg, c] = max over rows r with vt_map[r]==seg of in[r, c]; empty -> 0
// Strategy: order-preserving float->u32 encoding + native u32 atomicMax.
//   enc(f) = (bits & 0x80000000) ? ~bits : (bits | 0x80000000)  (monotone in f)
//   init out to enc(-inf) = 0x007FFFFF, scatter with atomicMax, decode pass
//   maps the untouched init value back to 0 (matching the jnp.isneginf fixup).

#define CCH 64

__device__ __forceinline__ unsigned enc_f32(float f) {
    unsigned u = __float_as_uint(f);
    return (u & 0x80000000u) ? ~u : (u | 0x80000000u);
}
__device__ __forceinline__ float dec_f32(unsigned u) {
    unsigned b = (u & 0x80000000u) ? (u & 0x7fffffffu) : ~u;
    return __uint_as_float(b);
}

static constexpr unsigned ENC_NEG_INF = 0x007FFFFFu;  // enc(-inf)

__global__ void pool_init_kernel(uint4* __restrict__ out, int n4) {
    int i = blockIdx.x * blockDim.x + threadIdx.x;
    if (i < n4) {
        out[i] = make_uint4(ENC_NEG_INF, ENC_NEG_INF, ENC_NEG_INF, ENC_NEG_INF);
    }
}

// One thread per (row, 4-channel group): 16 threads per row, float4 loads are
// fully coalesced across consecutive threads.
__global__ void pool_scatter_kernel(const float4* __restrict__ in,
                                    const int* __restrict__ vt_map,
                                    unsigned* __restrict__ out,
                                    int n_in, int vt_out) {
    int t = blockIdx.x * blockDim.x + threadIdx.x;
    int row = t >> 4;
    int g = t & 15;
    if (row >= n_in) return;
    int seg = vt_map[row];
    if (seg < 0 || seg >= vt_out) return;
    float4 v = in[row * 16 + g];
    unsigned* dst = out + (size_t)seg * CCH + g * 4;
    atomicMax(dst + 0, enc_f32(v.x));
    atomicMax(dst + 1, enc_f32(v.y));
    atomicMax(dst + 2, enc_f32(v.z));
    atomicMax(dst + 3, enc_f32(v.w));
}

__global__ void pool_decode_kernel(uint4* __restrict__ out, int n4) {
    int i = blockIdx.x * blockDim.x + threadIdx.x;
    if (i >= n4) return;
    uint4 u = out[i];
    float4 f;
    f.x = (u.x == ENC_NEG_INF) ? 0.0f : dec_f32(u.x);
    f.y = (u.y == ENC_NEG_INF) ? 0.0f : dec_f32(u.y);
    f.z = (u.z == ENC_NEG_INF) ? 0.0f : dec_f32(u.z);
    f.w = (u.w == ENC_NEG_INF) ? 0.0f : dec_f32(u.w);
    ((float4*)out)[i] = f;
}

extern "C" void kernel_launch(void* const* d_in, const int* in_sizes, int n_in_arr,
                              void* d_out, int out_size, void* d_ws, size_t ws_size,
                              hipStream_t stream) {
    const float4* in      = (const float4*)d_in[0];
    const int*    vt_map  = (const int*)d_in[2];   // vt_replace (d_in[1]) unused for max
    unsigned*     out_u   = (unsigned*)d_out;

    const int n_in  = in_sizes[0] / CCH;      // 1048576
    const int vt_out = out_size / CCH;        // 262144
    const int n4 = out_size / 4;              // 4194304 uint4 groups

    const int B = 256;

    pool_init_kernel<<<(n4 + B - 1) / B, B, 0, stream>>>((uint4*)out_u, n4);

    const int scatter_threads = n_in * 16;
    pool_scatter_kernel<<<(scatter_threads + B - 1) / B, B, 0, stream>>>(
        in, vt_map, out_u, n_in, vt_out);

    pool_decode_kernel<<<(n4 + B - 1) / B, B, 0, stream>>>((uint4*)out_u, n4);
}

// Round 2
// 489.199 us; speedup vs baseline: 2.0455x; 2.0455x over previous
//
#include <hip/hip_runtime.h>

// Segmented max pooling, gather formulation:
//   Phase 1: head[seg] = -1
//   Phase 2: per input row r: next[r] = atomicExch(&head[vt_map[r]], r)
//            (builds a per-segment linked list; 1M atomics vs 67M in the
//             scatter-atomicMax version, which was atomic-pipe-bound at 697us
//             with 1 GiB of fabric write traffic)
//   Phase 3: one wave per segment walks its list (wave-uniform loop, avg 4
//            rows); lane c maxes channel c; single coalesced 256B write.
// Fallback: if ws_size is too small for head+next, use the R1 atomic path.

#define CCH 64
#define NEG_INF (-__builtin_huge_valf())

__global__ void head_init_kernel(int* __restrict__ head, int vt_out) {
    int i = blockIdx.x * blockDim.x + threadIdx.x;
    if (i < vt_out) head[i] = -1;
}

__global__ void list_build_kernel(const int* __restrict__ vt_map,
                                  int* __restrict__ head,
                                  int* __restrict__ next,
                                  int n_in, int vt_out) {
    int r = blockIdx.x * blockDim.x + threadIdx.x;
    if (r >= n_in) return;
    int seg = vt_map[r];
    if (seg < 0 || seg >= vt_out) return;
    next[r] = atomicExch(&head[seg], r);
}

// blockDim = 256 -> 4 waves/block, one wave per output segment.
__global__ void gather_max_kernel(const float* __restrict__ in,
                                  const int* __restrict__ head,
                                  const int* __restrict__ next,
                                  float* __restrict__ out, int vt_out) {
    int wave = blockIdx.x * 4 + (threadIdx.x >> 6);
    int lane = threadIdx.x & 63;
    if (wave >= vt_out) return;
    int r = head[wave];              // wave-uniform (same addr, L1 broadcast)
    float m = NEG_INF;
    while (r >= 0) {
        m = fmaxf(m, in[(size_t)r * CCH + lane]);  // coalesced 256B row read
        r = next[r];                                // uniform dependent hop
    }
    out[(size_t)wave * CCH + lane] = (m == NEG_INF) ? 0.0f : m;
}

// ---- fallback (R1 path) ----
__device__ __forceinline__ unsigned enc_f32(float f) {
    unsigned u = __float_as_uint(f);
    return (u & 0x80000000u) ? ~u : (u | 0x80000000u);
}
__device__ __forceinline__ float dec_f32(unsigned u) {
    unsigned b = (u & 0x80000000u) ? (u & 0x7fffffffu) : ~u;
    return __uint_as_float(b);
}
static constexpr unsigned ENC_NEG_INF = 0x007FFFFFu;

__global__ void pool_init_kernel(uint4* __restrict__ out, int n4) {
    int i = blockIdx.x * blockDim.x + threadIdx.x;
    if (i < n4) out[i] = make_uint4(ENC_NEG_INF, ENC_NEG_INF, ENC_NEG_INF, ENC_NEG_INF);
}
__global__ void pool_scatter_kernel(const float4* __restrict__ in,
                                    const int* __restrict__ vt_map,
                                    unsigned* __restrict__ out,
                                    int n_in, int vt_out) {
    int t = blockIdx.x * blockDim.x + threadIdx.x;
    int row = t >> 4, g = t & 15;
    if (row >= n_in) return;
    int seg = vt_map[row];
    if (seg < 0 || seg >= vt_out) return;
    float4 v = in[row * 16 + g];
    unsigned* dst = out + (size_t)seg * CCH + g * 4;
    atomicMax(dst + 0, enc_f32(v.x));
    atomicMax(dst + 1, enc_f32(v.y));
    atomicMax(dst + 2, enc_f32(v.z));
    atomicMax(dst + 3, enc_f32(v.w));
}
__global__ void pool_decode_kernel(uint4* __restrict__ out, int n4) {
    int i = blockIdx.x * blockDim.x + threadIdx.x;
    if (i >= n4) return;
    uint4 u = out[i];
    float4 f;
    f.x = (u.x == ENC_NEG_INF) ? 0.0f : dec_f32(u.x);
    f.y = (u.y == ENC_NEG_INF) ? 0.0f : dec_f32(u.y);
    f.z = (u.z == ENC_NEG_INF) ? 0.0f : dec_f32(u.z);
    f.w = (u.w == ENC_NEG_INF) ? 0.0f : dec_f32(u.w);
    ((float4*)out)[i] = f;
}

extern "C" void kernel_launch(void* const* d_in, const int* in_sizes, int n_in_arr,
                              void* d_out, int out_size, void* d_ws, size_t ws_size,
                              hipStream_t stream) {
    const float* in     = (const float*)d_in[0];
    const int*   vt_map = (const int*)d_in[2];   // vt_replace (d_in[1]) unused
    float*       out    = (float*)d_out;

    const int n_in   = in_sizes[0] / CCH;   // 1048576
    const int vt_out = out_size / CCH;      // 262144
    const int B = 256;

    const size_t ws_needed = (size_t)(vt_out + n_in) * sizeof(int);
    if (ws_size >= ws_needed) {
        int* head = (int*)d_ws;
        int* next = head + vt_out;
        head_init_kernel<<<(vt_out + B - 1) / B, B, 0, stream>>>(head, vt_out);
        list_build_kernel<<<(n_in + B - 1) / B, B, 0, stream>>>(
            vt_map, head, next, n_in, vt_out);
        const int waves = vt_out;                 // one wave per segment
        gather_max_kernel<<<(waves + 3) / 4, B, 0, stream>>>(
            in, head, next, out, vt_out);
    } else {
        // workspace too small: R1 atomic-scatter fallback
        unsigned* out_u = (unsigned*)d_out;
        const int n4 = out_size / 4;
        pool_init_kernel<<<(n4 + B - 1) / B, B, 0, stream>>>((uint4*)out_u, n4);
        pool_scatter_kernel<<<(n_in * 16 + B - 1) / B, B, 0, stream>>>(
            (const float4*)in, vt_map, out_u, n_in, vt_out);
        pool_decode_kernel<<<(n4 + B - 1) / B, B, 0, stream>>>((uint4*)out_u, n4);
    }
}

// Round 3
// 485.765 us; speedup vs baseline: 2.0599x; 1.0071x over previous
//
#include <hip/hip_runtime.h>

// Segmented max pooling, CSR formulation.
//   K1 zero counts
//   K2 count:   rank[r] = atomicAdd(&cnt[vt_map[r]], 1)   (rank doubles as placement slot)
//   K3 block sums of cnt (256/block)
//   K4 exclusive scan of the 1024 block sums (single block)
//   K5 per-block exclusive scan -> offs[]
//   K6 place:   idx[offs[seg] + rank[r]] = r              (no atomics)
//   K7 gather:  one wave per segment; contiguous idx chunk load, then row
//               loads issued in 8-wide predicated batches so ~8 independent
//               HBM loads are in flight per wave (R2's linked-list walk had
//               ~1, which capped it at 1.5 TB/s).
// Fallbacks if ws too small: linked-list path (R2), then atomic-scatter (R1).

#define CCH 64
#define NEG_INF (-__builtin_huge_valf())

// ---------------- CSR path ----------------

__global__ void zero_kernel(int* __restrict__ p, int n) {
    int i = blockIdx.x * blockDim.x + threadIdx.x;
    if (i < n) p[i] = 0;
}

__global__ void count_kernel(const int* __restrict__ vt_map,
                             int* __restrict__ cnt,
                             int* __restrict__ rank,
                             int n_in, int vt_out) {
    int r = blockIdx.x * blockDim.x + threadIdx.x;
    if (r >= n_in) return;
    int seg = vt_map[r];
    if (seg < 0 || seg >= vt_out) { rank[r] = -1; return; }
    rank[r] = atomicAdd(&cnt[seg], 1);
}

__global__ void bsum_kernel(const int* __restrict__ cnt, int* __restrict__ bs,
                            int vt_out) {
    __shared__ int s[256];
    int b = blockIdx.x, t = threadIdx.x, i = b * 256 + t;
    s[t] = (i < vt_out) ? cnt[i] : 0;
    __syncthreads();
    for (int d = 128; d > 0; d >>= 1) {
        if (t < d) s[t] += s[t + d];
        __syncthreads();
    }
    if (t == 0) bs[b] = s[0];
}

__global__ void scan_bs_kernel(int* __restrict__ bs, int n) {
    __shared__ int s[1024];
    int t = threadIdx.x;
    s[t] = (t < n) ? bs[t] : 0;
    __syncthreads();
    for (int d = 1; d < 1024; d <<= 1) {
        int x = (t >= d) ? s[t - d] : 0;
        __syncthreads();
        s[t] += x;
        __syncthreads();
    }
    if (t < n) bs[t] = (t == 0) ? 0 : s[t - 1];   // exclusive
}

__global__ void offsets_kernel(const int* __restrict__ cnt,
                               const int* __restrict__ bs,
                               int* __restrict__ offs, int vt_out) {
    __shared__ int s[256];
    int b = blockIdx.x, t = threadIdx.x, i = b * 256 + t;
    int v = (i < vt_out) ? cnt[i] : 0;
    s[t] = v;
    __syncthreads();
    for (int d = 1; d < 256; d <<= 1) {
        int x = (t >= d) ? s[t - d] : 0;
        __syncthreads();
        s[t] += x;
        __syncthreads();
    }
    int excl = (t == 0) ? 0 : s[t - 1];
    if (i < vt_out) offs[i] = bs[b] + excl;
}

__global__ void place_kernel(const int* __restrict__ vt_map,
                             const int* __restrict__ rank,
                             const int* __restrict__ offs,
                             int* __restrict__ idx, int n_in, int vt_out) {
    int r = blockIdx.x * blockDim.x + threadIdx.x;
    if (r >= n_in) return;
    int seg = vt_map[r];
    if (seg < 0 || seg >= vt_out) return;
    idx[offs[seg] + rank[r]] = r;
}

__global__ __launch_bounds__(256) void csr_gather_kernel(
        const float* __restrict__ in,
        const int* __restrict__ cnt,
        const int* __restrict__ offs,
        const int* __restrict__ idx,
        float* __restrict__ out, int vt_out) {
    int wave = blockIdx.x * 4 + (threadIdx.x >> 6);
    int lane = threadIdx.x & 63;
    if (wave >= vt_out) return;
    int c = cnt[wave];
    int o = offs[wave];
    float m = NEG_INF;
    while (c > 0) {
        int take = (c < 64) ? c : 64;
        // contiguous chunk of row indices (single coalesced load per wave)
        int rvec = idx[o + ((lane < take) ? lane : (take - 1))];
        for (int j = 0; j < take; j += 8) {
            float v[8];
#pragma unroll
            for (int k = 0; k < 8; ++k) {
                int t = j + k;
                int rk = __shfl(rvec, (t < take) ? t : (take - 1), 64);
                v[k] = in[(size_t)rk * CCH + lane];   // 8 independent loads in flight
            }
#pragma unroll
            for (int k = 0; k < 8; ++k) {
                if (j + k < take) m = fmaxf(m, v[k]);
            }
        }
        o += take;
        c -= take;
    }
    out[(size_t)wave * CCH + lane] = (m == NEG_INF) ? 0.0f : m;
}

// ---------------- fallback: linked-list (R2) ----------------

__global__ void head_init_kernel(int* __restrict__ head, int vt_out) {
    int i = blockIdx.x * blockDim.x + threadIdx.x;
    if (i < vt_out) head[i] = -1;
}
__global__ void list_build_kernel(const int* __restrict__ vt_map,
                                  int* __restrict__ head, int* __restrict__ next,
                                  int n_in, int vt_out) {
    int r = blockIdx.x * blockDim.x + threadIdx.x;
    if (r >= n_in) return;
    int seg = vt_map[r];
    if (seg < 0 || seg >= vt_out) return;
    next[r] = atomicExch(&head[seg], r);
}
__global__ void gather_max_kernel(const float* __restrict__ in,
                                  const int* __restrict__ head,
                                  const int* __restrict__ next,
                                  float* __restrict__ out, int vt_out) {
    int wave = blockIdx.x * 4 + (threadIdx.x >> 6);
    int lane = threadIdx.x & 63;
    if (wave >= vt_out) return;
    int r = head[wave];
    float m = NEG_INF;
    while (r >= 0) {
        m = fmaxf(m, in[(size_t)r * CCH + lane]);
        r = next[r];
    }
    out[(size_t)wave * CCH + lane] = (m == NEG_INF) ? 0.0f : m;
}

// ---------------- fallback: atomic scatter (R1) ----------------

__device__ __forceinline__ unsigned enc_f32(float f) {
    unsigned u = __float_as_uint(f);
    return (u & 0x80000000u) ? ~u : (u | 0x80000000u);
}
__device__ __forceinline__ float dec_f32(unsigned u) {
    unsigned b = (u & 0x80000000u) ? (u & 0x7fffffffu) : ~u;
    return __uint_as_float(b);
}
static constexpr unsigned ENC_NEG_INF = 0x007FFFFFu;

__global__ void pool_init_kernel(uint4* __restrict__ out, int n4) {
    int i = blockIdx.x * blockDim.x + threadIdx.x;
    if (i < n4) out[i] = make_uint4(ENC_NEG_INF, ENC_NEG_INF, ENC_NEG_INF, ENC_NEG_INF);
}
__global__ void pool_scatter_kernel(const float4* __restrict__ in,
                                    const int* __restrict__ vt_map,
                                    unsigned* __restrict__ out, int n_in, int vt_out) {
    int t = blockIdx.x * blockDim.x + threadIdx.x;
    int row = t >> 4, g = t & 15;
    if (row >= n_in) return;
    int seg = vt_map[row];
    if (seg < 0 || seg >= vt_out) return;
    float4 v = in[row * 16 + g];
    unsigned* dst = out + (size_t)seg * CCH + g * 4;
    atomicMax(dst + 0, enc_f32(v.x));
    atomicMax(dst + 1, enc_f32(v.y));
    atomicMax(dst + 2, enc_f32(v.z));
    atomicMax(dst + 3, enc_f32(v.w));
}
__global__ void pool_decode_kernel(uint4* __restrict__ out, int n4) {
    int i = blockIdx.x * blockDim.x + threadIdx.x;
    if (i >= n4) return;
    uint4 u = out[i];
    float4 f;
    f.x = (u.x == ENC_NEG_INF) ? 0.0f : dec_f32(u.x);
    f.y = (u.y == ENC_NEG_INF) ? 0.0f : dec_f32(u.y);
    f.z = (u.z == ENC_NEG_INF) ? 0.0f : dec_f32(u.z);
    f.w = (u.w == ENC_NEG_INF) ? 0.0f : dec_f32(u.w);
    ((float4*)out)[i] = f;
}

// ---------------- launch ----------------

extern "C" void kernel_launch(void* const* d_in, const int* in_sizes, int n_in_arr,
                              void* d_out, int out_size, void* d_ws, size_t ws_size,
                              hipStream_t stream) {
    const float* in     = (const float*)d_in[0];
    const int*   vt_map = (const int*)d_in[2];   // vt_replace (d_in[1]) unused
    float*       out    = (float*)d_out;

    const int n_in   = in_sizes[0] / CCH;   // 1048576
    const int vt_out = out_size / CCH;      // 262144
    const int B = 256;
    const int nblk = (vt_out + 255) / 256;  // 1024

    const size_t ws_csr = ((size_t)vt_out * 2 + (size_t)n_in * 2 + nblk) * sizeof(int);
    const size_t ws_ll  = (size_t)(vt_out + n_in) * sizeof(int);

    if (ws_size >= ws_csr && nblk <= 1024) {
        int* cnt  = (int*)d_ws;
        int* offs = cnt + vt_out;
        int* rank = offs + vt_out;
        int* idx  = rank + n_in;
        int* bs   = idx + n_in;

        zero_kernel<<<(vt_out + B - 1) / B, B, 0, stream>>>(cnt, vt_out);
        count_kernel<<<(n_in + B - 1) / B, B, 0, stream>>>(vt_map, cnt, rank, n_in, vt_out);
        bsum_kernel<<<nblk, 256, 0, stream>>>(cnt, bs, vt_out);
        scan_bs_kernel<<<1, 1024, 0, stream>>>(bs, nblk);
        offsets_kernel<<<nblk, 256, 0, stream>>>(cnt, bs, offs, vt_out);
        place_kernel<<<(n_in + B - 1) / B, B, 0, stream>>>(vt_map, rank, offs, idx, n_in, vt_out);
        csr_gather_kernel<<<(vt_out + 3) / 4, B, 0, stream>>>(in, cnt, offs, idx, out, vt_out);
    } else if (ws_size >= ws_ll) {
        int* head = (int*)d_ws;
        int* next = head + vt_out;
        head_init_kernel<<<(vt_out + B - 1) / B, B, 0, stream>>>(head, vt_out);
        list_build_kernel<<<(n_in + B - 1) / B, B, 0, stream>>>(vt_map, head, next, n_in, vt_out);
        gather_max_kernel<<<(vt_out + 3) / 4, B, 0, stream>>>(in, head, next, out, vt_out);
    } else {
        unsigned* out_u = (unsigned*)d_out;
        const int n4 = out_size / 4;
        pool_init_kernel<<<(n4 + B - 1) / B, B, 0, stream>>>((uint4*)out_u, n4);
        pool_scatter_kernel<<<(n_in * 16 + B - 1) / B, B, 0, stream>>>(
            (const float4*)in, vt_map, out_u, n_in, vt_out);
        pool_decode_kernel<<<(n4 + B - 1) / B, B, 0, stream>>>((uint4*)out_u, n4);
    }
}

// Round 4
// 470.008 us; speedup vs baseline: 2.1290x; 1.0335x over previous
//
#include <hip/hip_runtime.h>

// Segmented max pooling, fixed-capacity bucket formulation.
//   K1 zero:        cnt[vt_out] = 0, ovf_n = 0                (1 MB)
//   K2 count+place: slot = atomicAdd(&cnt[seg],1);
//                   slot < 16 -> idx[seg*16+slot] = r
//                   else      -> overflow list (expected ~0 rows at lambda=4,
//                                but fully correct for any distribution)
//   K3 gather:      16-lane subgroup per segment (4 segments/wave);
//                   float4 row loads (16 x 16B = one 256B coalesced row),
//                   4-wide predicated batches for memory-level parallelism,
//                   no cross-lane reduction, 1 KiB contiguous store per wave.
// This removes R3's rank/bsum/scan/offsets/place machinery (~25 MB traffic,
// 4 launches) whose cost ate the CSR gather win.
// NOTE: dur_us carries a ~290 us harness floor (1 GiB d_ws 0xAA poison fill
// at ~160 us + d_out poison + input restore are inside the timed region).

#define CCH 64
#define CAP 16
#define NEG_INF (-__builtin_huge_valf())

__global__ void zero_kernel(int* __restrict__ p, int n) {
    int i = blockIdx.x * blockDim.x + threadIdx.x;
    if (i < n) p[i] = 0;
}

__global__ void count_place_kernel(const int* __restrict__ vt_map,
                                   int* __restrict__ cnt,
                                   int* __restrict__ idx,
                                   int* __restrict__ ovf_n,
                                   int* __restrict__ ovf_rows,
                                   int n_in, int vt_out) {
    int r = blockIdx.x * blockDim.x + threadIdx.x;
    if (r >= n_in) return;
    int seg = vt_map[r];
    if (seg < 0 || seg >= vt_out) return;
    int slot = atomicAdd(&cnt[seg], 1);
    if (slot < CAP) {
        idx[seg * CAP + slot] = r;
    } else {
        int e = atomicAdd(ovf_n, 1);
        ovf_rows[e] = r;           // capacity n_in reserved: cannot overflow
    }
}

__global__ __launch_bounds__(256) void bucket_gather_kernel(
        const float4* __restrict__ in4,
        const int* __restrict__ cnt,
        const int* __restrict__ idx,
        const int* __restrict__ ovf_n,
        const int* __restrict__ ovf_rows,
        const int* __restrict__ vt_map,
        float4* __restrict__ out4, int vt_out) {
    int wid  = blockIdx.x * 4 + (threadIdx.x >> 6);
    int lane = threadIdx.x & 63;
    int sub  = lane >> 4;          // subgroup 0..3, one segment each
    int g    = lane & 15;          // float4 column group within the row
    int seg  = wid * 4 + sub;
    if (seg >= vt_out) return;

    int c  = cnt[seg];
    int rv = idx[seg * CAP + g];   // 16 lanes hold the segment's 16 slots (64B coalesced)
    int cc = (c < CAP) ? c : CAP;

    float4 m = make_float4(NEG_INF, NEG_INF, NEG_INF, NEG_INF);
    for (int j = 0; j < cc; j += 4) {
        float4 v[4];
#pragma unroll
        for (int k = 0; k < 4; ++k) {
            int t  = j + k;
            int tt = (t < cc) ? t : (cc - 1);
            int rid = __shfl(rv, (sub << 4) + tt, 64);
            v[k] = in4[(size_t)rid * 16 + g];    // 4 independent 256B row reads in flight
        }
#pragma unroll
        for (int k = 0; k < 4; ++k) {
            if (j + k < cc) {
                m.x = fmaxf(m.x, v[k].x);
                m.y = fmaxf(m.y, v[k].y);
                m.z = fmaxf(m.z, v[k].z);
                m.w = fmaxf(m.w, v[k].w);
            }
        }
    }

    if (c > CAP) {                 // vanishingly rare; wave-uniform scan
        int ne = *ovf_n;
        for (int e = 0; e < ne; ++e) {
            int r = ovf_rows[e];
            if (vt_map[r] == seg) {
                float4 v = in4[(size_t)r * 16 + g];
                m.x = fmaxf(m.x, v.x);
                m.y = fmaxf(m.y, v.y);
                m.z = fmaxf(m.z, v.z);
                m.w = fmaxf(m.w, v.w);
            }
        }
    }

    float4 o;
    o.x = (m.x == NEG_INF) ? 0.0f : m.x;
    o.y = (m.y == NEG_INF) ? 0.0f : m.y;
    o.z = (m.z == NEG_INF) ? 0.0f : m.z;
    o.w = (m.w == NEG_INF) ? 0.0f : m.w;
    out4[(size_t)seg * 16 + g] = o;   // 4 consecutive segments -> 1KB contiguous/wave
}

// ---------------- fallback: atomic scatter (R1) ----------------

__device__ __forceinline__ unsigned enc_f32(float f) {
    unsigned u = __float_as_uint(f);
    return (u & 0x80000000u) ? ~u : (u | 0x80000000u);
}
__device__ __forceinline__ float dec_f32(unsigned u) {
    unsigned b = (u & 0x80000000u) ? (u & 0x7fffffffu) : ~u;
    return __uint_as_float(b);
}
static constexpr unsigned ENC_NEG_INF = 0x007FFFFFu;

__global__ void pool_init_kernel(uint4* __restrict__ out, int n4) {
    int i = blockIdx.x * blockDim.x + threadIdx.x;
    if (i < n4) out[i] = make_uint4(ENC_NEG_INF, ENC_NEG_INF, ENC_NEG_INF, ENC_NEG_INF);
}
__global__ void pool_scatter_kernel(const float4* __restrict__ in,
                                    const int* __restrict__ vt_map,
                                    unsigned* __restrict__ out, int n_in, int vt_out) {
    int t = blockIdx.x * blockDim.x + threadIdx.x;
    int row = t >> 4, g = t & 15;
    if (row >= n_in) return;
    int seg = vt_map[row];
    if (seg < 0 || seg >= vt_out) return;
    float4 v = in[row * 16 + g];
    unsigned* dst = out + (size_t)seg * CCH + g * 4;
    atomicMax(dst + 0, enc_f32(v.x));
    atomicMax(dst + 1, enc_f32(v.y));
    atomicMax(dst + 2, enc_f32(v.z));
    atomicMax(dst + 3, enc_f32(v.w));
}
__global__ void pool_decode_kernel(uint4* __restrict__ out, int n4) {
    int i = blockIdx.x * blockDim.x + threadIdx.x;
    if (i >= n4) return;
    uint4 u = out[i];
    float4 f;
    f.x = (u.x == ENC_NEG_INF) ? 0.0f : dec_f32(u.x);
    f.y = (u.y == ENC_NEG_INF) ? 0.0f : dec_f32(u.y);
    f.z = (u.z == ENC_NEG_INF) ? 0.0f : dec_f32(u.z);
    f.w = (u.w == ENC_NEG_INF) ? 0.0f : dec_f32(u.w);
    ((float4*)out)[i] = f;
}

// ---------------- launch ----------------

extern "C" void kernel_launch(void* const* d_in, const int* in_sizes, int n_in_arr,
                              void* d_out, int out_size, void* d_ws, size_t ws_size,
                              hipStream_t stream) {
    const float* in     = (const float*)d_in[0];
    const int*   vt_map = (const int*)d_in[2];   // vt_replace (d_in[1]) unused for max
    float*       out    = (float*)d_out;

    const int n_in   = in_sizes[0] / CCH;   // 1048576
    const int vt_out = out_size / CCH;      // 262144
    const int B = 256;

    // ws layout: cnt[vt_out] | ovf_n[1] | idx[vt_out*CAP] | ovf_rows[n_in]
    const size_t ws_needed =
        ((size_t)vt_out * (CAP + 1) + 1 + (size_t)n_in) * sizeof(int);

    if (ws_size >= ws_needed) {
        int* cnt      = (int*)d_ws;
        int* ovf_n    = cnt + vt_out;
        int* idx      = ovf_n + 1;
        int* ovf_rows = idx + (size_t)vt_out * CAP;

        zero_kernel<<<(vt_out + 1 + B - 1) / B, B, 0, stream>>>(cnt, vt_out + 1);
        count_place_kernel<<<(n_in + B - 1) / B, B, 0, stream>>>(
            vt_map, cnt, idx, ovf_n, ovf_rows, n_in, vt_out);
        const int nwave = (vt_out + 3) / 4;           // 4 segments per wave
        bucket_gather_kernel<<<(nwave + 3) / 4, B, 0, stream>>>(
            (const float4*)in, cnt, idx, ovf_n, ovf_rows, vt_map,
            (float4*)out, vt_out);
    } else {
        unsigned* out_u = (unsigned*)d_out;
        const int n4 = out_size / 4;
        pool_init_kernel<<<(n4 + B - 1) / B, B, 0, stream>>>((uint4*)out_u, n4);
        pool_scatter_kernel<<<(n_in * 16 + B - 1) / B, B, 0, stream>>>(
            (const float4*)in, vt_map, out_u, n_in, vt_out);
        pool_decode_kernel<<<(n4 + B - 1) / B, B, 0, stream>>>((uint4*)out_u, n4);
    }
}